// Round 12
// baseline (187.798 us; speedup 1.0000x reference)
//
#include <hip/hip_runtime.h>
#include <math.h>

#define BB 128
#define SS 200
#define MM 50
#define DKK 64
#define DVV 128
#define FF 64
#define NROW (BB*SS)   // 25600

#define WROW 64        // w padded layout: 64 floats/row, m<50 valid, rest zero
#define NFCB (NROW/64) // 400 k_fc blocks
#define WLDS 136       // k_pre/ea LDS bf16 row stride (2-way bank alias = free)
#define FLDS 200       // k_fc LDS bf16 read_w row stride (192+8)
#define NCH 16         // scan: t-chunks (waves) per block; 8x13 + 8x12 = 200 steps
#define MPQ 7          // scan: m-pairs per quarter-lane (28 pairs total; 26,27 = pad)
#define NSCB 100       // scores blocks inside k_pre (256 items each)

// workspace layout (floats)
#define W_OFF   0L
#define EA_OFF  (W_OFF + (long)NROW*WROW)        // interleaved (e,a) float2
#define R_OFF   (EA_OFF + (long)NROW*DVV*2)
#define ACC_OFF (R_OFF + (long)NROW*DVV)         // [0]=bce [1]=cnt [2]=counter bits

typedef __attribute__((ext_vector_type(8))) short bf16x8;   // 8 bf16 (4 VGPRs)
typedef __attribute__((ext_vector_type(4))) float f32x4;
typedef __attribute__((ext_vector_type(2))) float f32x2;    // -> v_pk_*_f32

__device__ __forceinline__ short f2bf(float f) {   // RNE fp32->bf16
    unsigned u = __builtin_bit_cast(unsigned, f);
    u += 0x7fff + ((u >> 16) & 1);
    return (short)(u >> 16);
}
__device__ __forceinline__ bf16x8 cvt8(const float* p) {
    float4 lo = *(const float4*)p;
    float4 hi = *(const float4*)(p + 4);
    bf16x8 f;
    f[0] = f2bf(lo.x); f[1] = f2bf(lo.y); f[2] = f2bf(lo.z); f[3] = f2bf(lo.w);
    f[4] = f2bf(hi.x); f[5] = f2bf(hi.y); f[6] = f2bf(hi.z); f[7] = f2bf(hi.w);
    return f;
}

// ---------------- Kernel 1: fused scores + ea (independent block types) ----------------
__global__ __launch_bounds__(256) void k_pre(const int* __restrict__ q_data,
                                             const float* __restrict__ q_embed_w,
                                             const float* __restrict__ mem_key,
                                             const int* __restrict__ qa_data,
                                             const float* __restrict__ qa_embed_w,
                                             const float* __restrict__ erase_w,
                                             const float* __restrict__ erase_b,
                                             const float* __restrict__ add_w,
                                             const float* __restrict__ add_b,
                                             float* __restrict__ w_out,
                                             float* __restrict__ EA,
                                             float* __restrict__ acc) {
    __shared__ union {
        short  wl[2 * 128 * WLDS];   // ea branch: bf16 weights, 69.6 KB
        float4 mk[MM * 16];          // scores branch: mem_key, 12.8 KB
    } sh;
    int tid = threadIdx.x;
    int bid = blockIdx.x;

    if (bid < NSCB) {
        // ---------- scores branch ----------
        if (bid == 0 && tid == 0) {
            acc[0] = 0.f; acc[1] = 0.f;
            ((unsigned*)acc)[2] = 0u;
        }
        const float4* mkg = (const float4*)mem_key;
        for (int i = tid; i < MM * 16; i += 256) sh.mk[i] = mkg[i];
        __syncthreads();

        int item = bid * 256 + tid;
        int qidx = q_data[item];
        const float4* qg = (const float4*)(q_embed_w + (long)qidx * DKK);
        float4 q[16];
#pragma unroll
        for (int i = 0; i < 16; i++) q[i] = qg[i];

        float s[MM];
        float mx = -1e30f;
#pragma unroll 2
        for (int m = 0; m < MM; m++) {
            float a = 0.f;
#pragma unroll
            for (int k4 = 0; k4 < 16; k4++) {
                float4 mkv = sh.mk[m * 16 + k4];
                float4 qv = q[k4];
                a = fmaf(qv.x, mkv.x, a);
                a = fmaf(qv.y, mkv.y, a);
                a = fmaf(qv.z, mkv.z, a);
                a = fmaf(qv.w, mkv.w, a);
            }
            s[m] = a;
            mx = fmaxf(mx, a);
        }
        float sum = 0.f;
#pragma unroll
        for (int m = 0; m < MM; m++) { s[m] = expf(s[m] - mx); sum += s[m]; }
        float inv = 1.f / sum;

        float* wo = w_out + (long)item * WROW;
#pragma unroll
        for (int m = 0; m < MM; m++) wo[m] = s[m] * inv;
#pragma unroll
        for (int m = MM; m < WROW; m++) wo[m] = 0.f;
        return;
    }

    // ---------- ea branch ----------
    int r0 = (bid - NSCB) * 64;
    int lane = tid & 63;
    int wv = tid >> 6;          // wave 0..3
    int n = lane & 15;
    int quad = lane >> 4;       // 0..3

    for (int i = tid; i < 8192; i += 256) {
        int mat = i >> 12;
        int r = (i >> 5) & 127;
        int p = i & 31;
        float4 src = *(const float4*)((mat ? add_w : erase_w) + r * 128 + p * 4);
        short4 d;
        d.x = f2bf(src.x); d.y = f2bf(src.y); d.z = f2bf(src.z); d.w = f2bf(src.w);
        *(short4*)(sh.wl + (mat * 128 + r) * WLDS + p * 4) = d;
    }

    int arow = r0 + wv * 16 + n;
    int qidx = qa_data[arow];
    const float* qp = qa_embed_w + (long)qidx * DVV + quad * 8;
    bf16x8 afrag[4];
#pragma unroll
    for (int kb = 0; kb < 4; kb++) afrag[kb] = cvt8(qp + kb * 32);

    float eb_[8], ab_[8];
#pragma unroll
    for (int vt = 0; vt < 8; vt++) {
        eb_[vt] = erase_b[vt * 16 + n];
        ab_[vt] = add_b[vt * 16 + n];
    }
    __syncthreads();

    int rowbase = r0 + wv * 16 + quad * 4;
#pragma unroll 2
    for (int vt = 0; vt < 8; vt++) {
        int vrow = vt * 16 + n;
        f32x4 ae = {0.f, 0.f, 0.f, 0.f};
        f32x4 aa = {0.f, 0.f, 0.f, 0.f};
#pragma unroll
        for (int kb = 0; kb < 4; kb++) {
            bf16x8 be = *(const bf16x8*)(sh.wl + vrow * WLDS + kb * 32 + quad * 8);
            bf16x8 ba = *(const bf16x8*)(sh.wl + (128 + vrow) * WLDS + kb * 32 + quad * 8);
            ae = __builtin_amdgcn_mfma_f32_16x16x32_bf16(afrag[kb], be, ae, 0, 0, 0);
            aa = __builtin_amdgcn_mfma_f32_16x16x32_bf16(afrag[kb], ba, aa, 0, 0, 0);
        }
        int v = vt * 16 + n;
        float eb = eb_[vt], ab = ab_[vt];
#pragma unroll
        for (int r = 0; r < 4; r++) {
            float ev = 1.f / (1.f + __expf(-(ae[r] + eb)));
            float av = 2.f / (1.f + __expf(-2.f * (aa[r] + ab))) - 1.f;
            float2 o; o.x = ev; o.y = av;
            *(float2*)(EA + (((long)(rowbase + r)) * DVV + v) * 2) = o;
        }
    }
}

// ---------------- Kernel 2: affine scan — 16 t-chunks x quarter-wave m-split ----------------
// R10 ~39us: 4 waves/SIMD, no spill, but 50 serial steps of inline-ds_read latency.
// R11 48us: source-level w reg-double-buffer — compiler re-folded it (VGPR 80), no win.
//   TLP is the only lever that has paid; ILP attempts failed 3x (R7 SMEM, R8 spill, R11).
// R12: make the 64-VGPR@1024thr cap (proven R1-R3) a FEATURE. Block = 1024 thr =
//   16 waves = 16 t-chunks (8x13+8x12; half R10's serial depth). Lane = quad*16+vl:
//   each quarter-wave owns 7 m-pairs (28 total, 26-27 pad w==0), same 16 v-cols.
//   A2/B2=28 + Mv=14 + misc ~= 56 VGPR < 64 -> no spill. Grid = BB x 8 v-groups =
//   1024 blocks; LDS 54.8KB -> 2 blocks/CU = 8 waves/SIMD (2x R10). rd closes with
//   shfl_xor(16)+shfl_xor(32); quad 0 writes R. Lean passes kept (chunk 0 scans
//   directly; chunk 15 skips pass 1). w reads: 7x ds_read_b64, 4 uniform addrs/wave,
//   disjoint banks -> conflict-free broadcast.
__device__ __forceinline__ void scan_pass1(const float2* __restrict__ wp, int j0, int L,
                                           const float* __restrict__ eab,
                                           f32x2* A2, f32x2* B2) {
    const f32x2 one = {1.f, 1.f};
    float2 e0 = *(const float2*)eab;
    float2 e1 = *(const float2*)(eab + (long)1 * DVV * 2);
#pragma unroll 1
    for (int t = 0; t < L; t++) {
        int tp = (t + 2 < L) ? t + 2 : L - 1;
        float2 en = *(const float2*)(eab + (long)tp * DVV * 2);
        f32x2 ne2 = {-e0.x, -e0.x};
        f32x2 a2  = {e0.y, e0.y};
#pragma unroll
        for (int j = 0; j < MPQ; j++) {
            float2 q = wp[t * 32 + j0 + j];
            f32x2 w2 = {q.x, q.y};
            f32x2 al = w2 * ne2 + one;              // 1 - w*e
            A2[j] = A2[j] * al;
            B2[j] = al * B2[j] + w2 * a2;
        }
        e0 = e1; e1 = en;
    }
}

__device__ __forceinline__ void scan_pass2(const float2* __restrict__ wp, int j0, int L,
                                           const float* __restrict__ eab,
                                           float* __restrict__ Rb, int quad,
                                           f32x2* Mv) {
    float2 e0 = *(const float2*)eab;
    float2 e1 = *(const float2*)(eab + (long)1 * DVV * 2);
#pragma unroll 1
    for (int t = 0; t < L; t++) {
        int tp = (t + 2 < L) ? t + 2 : L - 1;
        float2 en = *(const float2*)(eab + (long)tp * DVV * 2);
        f32x2 ne2 = {-e0.x, -e0.x};
        f32x2 a2  = {e0.y, e0.y};
        f32x2 rd  = {0.f, 0.f};
#pragma unroll
        for (int j = 0; j < MPQ; j++) {
            float2 q = wp[t * 32 + j0 + j];
            f32x2 w2 = {q.x, q.y};
            rd = rd + w2 * Mv[j];                   // read uses PRE-update Mv
            f32x2 s = ne2 * Mv[j] + a2;             // a - e*Mv
            Mv[j] = Mv[j] + w2 * s;
        }
        float r = rd.x + rd.y;
        r += __shfl_xor(r, 16, 64);                 // combine the 4 m-quarters
        r += __shfl_xor(r, 32, 64);
        if (quad == 0) Rb[t * DVV] = r;
        e0 = e1; e1 = en;
    }
}

__global__ __launch_bounds__(1024, 1) void k_scan(const float* __restrict__ w_pad,
                                                  const float* __restrict__ EA,
                                                  const float* __restrict__ init_mv,
                                                  float* __restrict__ R) {
    __shared__ float Wl[SS * WROW];    // 51.2 KB: this block's w tile
    __shared__ float Sb[56 * 16];      // 3.5 KB boundary state (56 m-rows x 16 v)
    int b   = blockIdx.x >> 3;
    int vg  = blockIdx.x & 7;
    int tid = threadIdx.x;
    int lane  = tid & 63;
    int chunk = tid >> 6;              // wave id = chunk (0..15)
    int quad = lane >> 4;              // m-quarter (pairs quad*7 .. quad*7+6)
    int vl = lane & 15;
    int v  = vg * 16 + vl;
    int j0 = quad * MPQ;               // pair offset 0,7,14,21
    int t0 = (chunk < 8) ? chunk * 13 : 104 + (chunk - 8) * 12;
    int L  = (chunk < 8) ? 13 : 12;

    // stage w (coalesced float4), read once per block
    {
        const float4* wg = (const float4*)(w_pad + (long)b * SS * WROW);
        float4* wl4 = (float4*)Wl;
        for (int i = tid; i < SS * WROW / 4; i += 1024) wl4[i] = wg[i];
    }
    __syncthreads();

    const float2* wp  = (const float2*)(Wl + t0 * WROW);   // uniform per quarter-wave
    const float*  eab = EA + (((long)b * SS + t0) * DVV + v) * 2;
    float*        Rb  = R + ((long)b * SS + t0) * DVV + v;

    const f32x2 one = {1.f, 1.f};
    f32x2 A2[MPQ], B2[MPQ];
    f32x2 Mv[MPQ];

    if (chunk == 0) {
        // real scan directly; final Mv IS the boundary for chunk 1
#pragma unroll
        for (int j = 0; j < MPQ; j++) {
            int m0 = 2 * (j0 + j), m1 = m0 + 1;
            if (m0 > MM - 2) m0 = MM - 2;   // pad pairs (m 50..55): w==0 there, value
            if (m1 > MM - 1) m1 = MM - 1;   // irrelevant but must stay in-bounds
            Mv[j].x = init_mv[m0 * DVV + v];
            Mv[j].y = init_mv[m1 * DVV + v];
        }
        scan_pass2(wp, j0, L, eab, Rb, quad, Mv);
#pragma unroll
        for (int j = 0; j < MPQ; j++) {
            Sb[(2 * (j0 + j)) * 16 + vl] = Mv[j].x;
            Sb[(2 * (j0 + j) + 1) * 16 + vl] = Mv[j].y;
        }
    } else if (chunk < NCH - 1) {
#pragma unroll
        for (int j = 0; j < MPQ; j++) { A2[j] = one; B2[j] = (f32x2){0.f, 0.f}; }
        scan_pass1(wp, j0, L, eab, A2, B2);
    }
    // chunk 15: no pass 1 needed (its A,B was never consumed)
    __syncthreads();

    for (int c = 1; c < NCH; c++) {
        if (chunk == c) {
#pragma unroll
            for (int j = 0; j < MPQ; j++) {
                Mv[j].x = Sb[(2 * (j0 + j)) * 16 + vl];
                Mv[j].y = Sb[(2 * (j0 + j) + 1) * 16 + vl];
            }
            if (c < NCH - 1) {
#pragma unroll
                for (int j = 0; j < MPQ; j++) {
                    f32x2 nb = A2[j] * Mv[j] + B2[j];
                    Sb[(2 * (j0 + j)) * 16 + vl] = nb.x;
                    Sb[(2 * (j0 + j) + 1) * 16 + vl] = nb.y;
                }
            }
        }
        __syncthreads();
    }

    if (chunk > 0) scan_pass2(wp, j0, L, eab, Rb, quad, Mv);
}

// ---------------- Kernel 3: FC head via bf16 MFMA + BCE + fused loss ----------------
// 64 rows x 64 f per block, 4 waves. K=192 ([R||q_e]). read_w staged bf16 in LDS
// (25.6 KB -> 6 blocks/CU). A-frags global->reg. D: col=f=lane&15, row=quad*4+reg.
__global__ __launch_bounds__(256) void k_fc(const float* __restrict__ Rr,
                                            const int* __restrict__ q_data,
                                            const float* __restrict__ q_embed_w,
                                            const float* __restrict__ read_w,
                                            const float* __restrict__ read_b,
                                            const float* __restrict__ pred_w,
                                            const float* __restrict__ pred_b,
                                            const float* __restrict__ target,
                                            float* __restrict__ out,
                                            float* __restrict__ acc) {
    __shared__ short Wl[64 * FLDS];   // 25.6 KB
    __shared__ float2 red[4];
    int tid = threadIdx.x;
    int r0 = blockIdx.x * 64;
    int lane = tid & 63;
    int wv = tid >> 6;          // wave 0..3
    int n = lane & 15;
    int quad = lane >> 4;       // 0..3

    // stage read_w -> bf16 LDS (64 f-rows x 48 float4)
    for (int i = tid; i < 3072; i += 256) {
        int f = i / 48, p = i - f * 48;
        float4 src = *(const float4*)(read_w + f * 192 + p * 4);
        short4 d;
        d.x = f2bf(src.x); d.y = f2bf(src.y); d.z = f2bf(src.z); d.w = f2bf(src.w);
        *(short4*)(Wl + f * FLDS + p * 4) = d;
    }

    // A-frags: row = r0 + wv*16 + n; k = kb*32 + quad*8 + j; kb 0..3 from R, 4..5 from q_e
    int arow = r0 + wv * 16 + n;
    const float* rp = Rr + (long)arow * DVV + quad * 8;
    int qi = q_data[arow];
    const float* qp = q_embed_w + (long)qi * DKK + quad * 8;
    bf16x8 afrag[6];
#pragma unroll
    for (int kb = 0; kb < 4; kb++) afrag[kb] = cvt8(rp + kb * 32);
#pragma unroll
    for (int kb = 0; kb < 2; kb++) afrag[4 + kb] = cvt8(qp + kb * 32);

    // per-lane epilogue constants for f = ft*16+n
    float rb_[4], pw_[4];
#pragma unroll
    for (int ft = 0; ft < 4; ft++) {
        rb_[ft] = read_b[ft * 16 + n];
        pw_[ft] = pred_w[ft * 16 + n];
    }
    float pb = pred_b[0];
    __syncthreads();

    int rowbase = r0 + wv * 16 + quad * 4;
    float pv[4] = {0.f, 0.f, 0.f, 0.f};   // pred-dot partials per row-reg
#pragma unroll
    for (int ft = 0; ft < 4; ft++) {
        int f = ft * 16 + n;               // B-frag: lane's column = read_w row
        f32x4 ac = {0.f, 0.f, 0.f, 0.f};
#pragma unroll
        for (int kb = 0; kb < 6; kb++) {
            bf16x8 bfr = *(const bf16x8*)(Wl + f * FLDS + kb * 32 + quad * 8);
            ac = __builtin_amdgcn_mfma_f32_16x16x32_bf16(afrag[kb], bfr, ac, 0, 0, 0);
        }
        float rb = rb_[ft], pw = pw_[ft];
#pragma unroll
        for (int r = 0; r < 4; r++) {
            float h = 2.f / (1.f + __expf(-2.f * (ac[r] + rb))) - 1.f;   // tanh
            pv[r] = fmaf(pw, h, pv[r]);
        }
    }

    float bce_sum = 0.f, cnt = 0.f;
#pragma unroll
    for (int r = 0; r < 4; r++) {
        float p = pv[r];
        p += __shfl_xor(p, 1, 64);
        p += __shfl_xor(p, 2, 64);
        p += __shfl_xor(p, 4, 64);
        p += __shfl_xor(p, 8, 64);
        if (n == 0) {
            int row = rowbase + r;
            float tgt = target[row];
            float logit = p + pb;
            float prob = 0.f;
            if (tgt >= 0.f) {
                prob = 1.f / (1.f + __expf(-logit));
                float bce = fmaxf(logit, 0.f) - logit * tgt + log1pf(__expf(-fabsf(logit)));
                bce_sum += bce;
                cnt += 1.f;
            }
            out[1 + row] = prob;
        }
    }
    // reduce over quads (values live on lanes 0,16,32,48)
    bce_sum += __shfl_xor(bce_sum, 16, 64);
    bce_sum += __shfl_xor(bce_sum, 32, 64);
    cnt     += __shfl_xor(cnt, 16, 64);
    cnt     += __shfl_xor(cnt, 32, 64);
    if (lane == 0) { red[wv].x = bce_sum; red[wv].y = cnt; }
    __syncthreads();
    if (tid == 0) {
        float bsum = red[0].x + red[1].x + red[2].x + red[3].x;
        float csum = red[0].y + red[1].y + red[2].y + red[3].y;
        atomicAdd(&acc[0], bsum);
        atomicAdd(&acc[1], csum);
        __threadfence();
        unsigned prev = atomicAdd((unsigned*)acc + 2, 1u);
        if (prev == NFCB - 1) {          // last block computes the loss
            __threadfence();
            float B = atomicAdd(&acc[0], 0.f);
            float C = atomicAdd(&acc[1], 0.f);
            out[0] = B / fmaxf(C, 1.f);
        }
    }
}

extern "C" void kernel_launch(void* const* d_in, const int* in_sizes, int n_in,
                              void* d_out, int out_size, void* d_ws, size_t ws_size,
                              hipStream_t stream) {
    const int*   q_data     = (const int*)d_in[0];
    const int*   qa_data    = (const int*)d_in[1];
    const float* target     = (const float*)d_in[2];
    const float* q_embed_w  = (const float*)d_in[3];
    const float* qa_embed_w = (const float*)d_in[4];
    const float* mem_key    = (const float*)d_in[5];
    const float* init_mv    = (const float*)d_in[6];
    const float* erase_w    = (const float*)d_in[7];
    const float* erase_b    = (const float*)d_in[8];
    const float* add_w      = (const float*)d_in[9];
    const float* add_b      = (const float*)d_in[10];
    const float* read_w     = (const float*)d_in[11];
    const float* read_b     = (const float*)d_in[12];
    const float* pred_w     = (const float*)d_in[13];
    const float* pred_b     = (const float*)d_in[14];
    float* out = (float*)d_out;
    float* ws  = (float*)d_ws;

    float* w_all = ws + W_OFF;
    float* EA    = ws + EA_OFF;
    float* R     = ws + R_OFF;
    float* acc   = ws + ACC_OFF;

    k_pre<<<NSCB + NROW / 64, 256, 0, stream>>>(q_data, q_embed_w, mem_key,
                                                qa_data, qa_embed_w,
                                                erase_w, erase_b, add_w, add_b,
                                                w_all, EA, acc);
    k_scan<<<BB * 8, 1024, 0, stream>>>(w_all, EA, init_mv, R);
    k_fc<<<NFCB, 256, 0, stream>>>(R, q_data, q_embed_w, read_w, read_b,
                                   pred_w, pred_b, target, out, acc);
}

// Round 13
// 172.328 us; speedup vs baseline: 1.0898x; 1.0898x over previous
//
#include <hip/hip_runtime.h>
#include <math.h>

#define BB 128
#define SS 200
#define MM 50
#define DKK 64
#define DVV 128
#define FF 64
#define NROW (BB*SS)   // 25600

#define WROW 64        // w padded layout: half0 m0-25 @ 0..25, half1 m26-49 @ 32..55, rest zero
#define NFCB (NROW/64) // 400 k_fc blocks
#define WLDS 136       // k_pre/ea LDS bf16 row stride (2-way bank alias = free)
#define FLDS 200       // k_fc LDS bf16 read_w row stride (192+8)
#define CLEN 25        // scan: steps per chunk (8 chunks x 25 = 200)
#define MPH 13         // scan: m-pairs per half-wave (26 pairs total; pair 25 = pad)
#define NSCB 100       // scores blocks inside k_pre (256 items each)

// workspace layout (floats)
#define W_OFF   0L
#define EA_OFF  (W_OFF + (long)NROW*WROW)        // interleaved (e,a) float2
#define R_OFF   (EA_OFF + (long)NROW*DVV*2)
#define ACC_OFF (R_OFF + (long)NROW*DVV)         // [0]=bce [1]=cnt [2]=counter bits

typedef __attribute__((ext_vector_type(8))) short bf16x8;   // 8 bf16 (4 VGPRs)
typedef __attribute__((ext_vector_type(4))) float f32x4;
typedef __attribute__((ext_vector_type(2))) float f32x2;    // -> v_pk_*_f32

__device__ __forceinline__ short f2bf(float f) {   // RNE fp32->bf16
    unsigned u = __builtin_bit_cast(unsigned, f);
    u += 0x7fff + ((u >> 16) & 1);
    return (short)(u >> 16);
}
__device__ __forceinline__ bf16x8 cvt8(const float* p) {
    float4 lo = *(const float4*)p;
    float4 hi = *(const float4*)(p + 4);
    bf16x8 f;
    f[0] = f2bf(lo.x); f[1] = f2bf(lo.y); f[2] = f2bf(lo.z); f[3] = f2bf(lo.w);
    f[4] = f2bf(hi.x); f[5] = f2bf(hi.y); f[6] = f2bf(hi.z); f[7] = f2bf(hi.w);
    return f;
}

// ---------------- Kernel 1: fused scores + ea (independent block types) ----------------
__global__ __launch_bounds__(256) void k_pre(const int* __restrict__ q_data,
                                             const float* __restrict__ q_embed_w,
                                             const float* __restrict__ mem_key,
                                             const int* __restrict__ qa_data,
                                             const float* __restrict__ qa_embed_w,
                                             const float* __restrict__ erase_w,
                                             const float* __restrict__ erase_b,
                                             const float* __restrict__ add_w,
                                             const float* __restrict__ add_b,
                                             float* __restrict__ w_out,
                                             float* __restrict__ EA,
                                             float* __restrict__ acc) {
    __shared__ union {
        short  wl[2 * 128 * WLDS];   // ea branch: bf16 weights, 69.6 KB
        float4 mk[MM * 16];          // scores branch: mem_key, 12.8 KB
    } sh;
    int tid = threadIdx.x;
    int bid = blockIdx.x;

    if (bid < NSCB) {
        // ---------- scores branch ----------
        if (bid == 0 && tid == 0) {
            acc[0] = 0.f; acc[1] = 0.f;
            ((unsigned*)acc)[2] = 0u;
        }
        const float4* mkg = (const float4*)mem_key;
        for (int i = tid; i < MM * 16; i += 256) sh.mk[i] = mkg[i];
        __syncthreads();

        int item = bid * 256 + tid;
        int qidx = q_data[item];
        const float4* qg = (const float4*)(q_embed_w + (long)qidx * DKK);
        float4 q[16];
#pragma unroll
        for (int i = 0; i < 16; i++) q[i] = qg[i];

        float s[MM];
        float mx = -1e30f;
#pragma unroll 2
        for (int m = 0; m < MM; m++) {
            float a = 0.f;
#pragma unroll
            for (int k4 = 0; k4 < 16; k4++) {
                float4 mkv = sh.mk[m * 16 + k4];
                float4 qv = q[k4];
                a = fmaf(qv.x, mkv.x, a);
                a = fmaf(qv.y, mkv.y, a);
                a = fmaf(qv.z, mkv.z, a);
                a = fmaf(qv.w, mkv.w, a);
            }
            s[m] = a;
            mx = fmaxf(mx, a);
        }
        float sum = 0.f;
#pragma unroll
        for (int m = 0; m < MM; m++) { s[m] = expf(s[m] - mx); sum += s[m]; }
        float inv = 1.f / sum;

        // aligned-half layout: m<26 at [m]; m>=26 at [m+6] (half1 base = float 32);
        // zeros at 26..31 and 56..63 so every half-slice is 128B-aligned for b128 reads
        float* wo = w_out + (long)item * WROW;
#pragma unroll
        for (int m = 0; m < 26; m++) wo[m] = s[m] * inv;
#pragma unroll
        for (int m = 26; m < MM; m++) wo[m + 6] = s[m] * inv;
#pragma unroll
        for (int m = 26; m < 32; m++) wo[m] = 0.f;
#pragma unroll
        for (int m = MM + 6; m < WROW; m++) wo[m] = 0.f;
        return;
    }

    // ---------- ea branch ----------
    int r0 = (bid - NSCB) * 64;
    int lane = tid & 63;
    int wv = tid >> 6;          // wave 0..3
    int n = lane & 15;
    int quad = lane >> 4;       // 0..3

    for (int i = tid; i < 8192; i += 256) {
        int mat = i >> 12;
        int r = (i >> 5) & 127;
        int p = i & 31;
        float4 src = *(const float4*)((mat ? add_w : erase_w) + r * 128 + p * 4);
        short4 d;
        d.x = f2bf(src.x); d.y = f2bf(src.y); d.z = f2bf(src.z); d.w = f2bf(src.w);
        *(short4*)(sh.wl + (mat * 128 + r) * WLDS + p * 4) = d;
    }

    int arow = r0 + wv * 16 + n;
    int qidx = qa_data[arow];
    const float* qp = qa_embed_w + (long)qidx * DVV + quad * 8;
    bf16x8 afrag[4];
#pragma unroll
    for (int kb = 0; kb < 4; kb++) afrag[kb] = cvt8(qp + kb * 32);

    float eb_[8], ab_[8];
#pragma unroll
    for (int vt = 0; vt < 8; vt++) {
        eb_[vt] = erase_b[vt * 16 + n];
        ab_[vt] = add_b[vt * 16 + n];
    }
    __syncthreads();

    int rowbase = r0 + wv * 16 + quad * 4;
#pragma unroll 2
    for (int vt = 0; vt < 8; vt++) {
        int vrow = vt * 16 + n;
        f32x4 ae = {0.f, 0.f, 0.f, 0.f};
        f32x4 aa = {0.f, 0.f, 0.f, 0.f};
#pragma unroll
        for (int kb = 0; kb < 4; kb++) {
            bf16x8 be = *(const bf16x8*)(sh.wl + vrow * WLDS + kb * 32 + quad * 8);
            bf16x8 ba = *(const bf16x8*)(sh.wl + (128 + vrow) * WLDS + kb * 32 + quad * 8);
            ae = __builtin_amdgcn_mfma_f32_16x16x32_bf16(afrag[kb], be, ae, 0, 0, 0);
            aa = __builtin_amdgcn_mfma_f32_16x16x32_bf16(afrag[kb], ba, aa, 0, 0, 0);
        }
        int v = vt * 16 + n;
        float eb = eb_[vt], ab = ab_[vt];
#pragma unroll
        for (int r = 0; r < 4; r++) {
            float ev = 1.f / (1.f + __expf(-(ae[r] + eb)));
            float av = 2.f / (1.f + __expf(-2.f * (aa[r] + ab))) - 1.f;
            float2 o; o.x = ev; o.y = av;
            *(float2*)(EA + (((long)(rowbase + r)) * DVV + v) * 2) = o;
        }
    }
}

// ---------------- Kernel 2: affine scan — R10 structure + b128-aligned w halves ----------------
// R10 (best, 39us): m-half split, 4 waves/SIMD, no spill; VALU floor ~15us, rest stall.
// R11 (48us): reg double-buffer re-folded by compiler. R12 (50.7us): 8 waves/SIMD via
//   16-chunk quarter-split — occupancy 71% but overhead (8x staging dup, pads, barriers)
//   ate it. Conclusion: 4 waves/SIMD + minimal overhead is the frontier; shave issues.
// R13: identical to R10 except w rows use the aligned-half layout (half1 base = float 32,
//   128B-aligned) so each half-wave's 13 pairs read as 7x ds_read_b128 instead of
//   13x ds_read_b64. Halves alias the same banks: 2-way uniform broadcast = free (m136).
__device__ __forceinline__ void scan_pass1(const float4* __restrict__ wp4,
                                           const float* __restrict__ eab,
                                           f32x2* A2, f32x2* B2) {
    const f32x2 one = {1.f, 1.f};
    float2 e0 = *(const float2*)eab;
    float2 e1 = *(const float2*)(eab + (long)1 * DVV * 2);
#pragma unroll 1
    for (int t = 0; t < CLEN; t++) {
        int tp = (t + 2 < CLEN) ? t + 2 : CLEN - 1;
        float2 en = *(const float2*)(eab + (long)tp * DVV * 2);
        f32x2 ne2 = {-e0.x, -e0.x};
        f32x2 a2  = {e0.y, e0.y};
#pragma unroll
        for (int j = 0; j < MPH; j++) {
            float4 q = wp4[t * 16 + (j >> 1)];
            f32x2 w2 = (j & 1) ? (f32x2){q.z, q.w} : (f32x2){q.x, q.y};
            f32x2 al = w2 * ne2 + one;              // 1 - w*e
            A2[j] = A2[j] * al;
            B2[j] = al * B2[j] + w2 * a2;
        }
        e0 = e1; e1 = en;
    }
}

__device__ __forceinline__ void scan_pass2(const float4* __restrict__ wp4,
                                           const float* __restrict__ eab,
                                           float* __restrict__ Rb, int mh,
                                           f32x2* Mv) {
    float2 e0 = *(const float2*)eab;
    float2 e1 = *(const float2*)(eab + (long)1 * DVV * 2);
#pragma unroll 1
    for (int t = 0; t < CLEN; t++) {
        int tp = (t + 2 < CLEN) ? t + 2 : CLEN - 1;
        float2 en = *(const float2*)(eab + (long)tp * DVV * 2);
        f32x2 ne2 = {-e0.x, -e0.x};
        f32x2 a2  = {e0.y, e0.y};
        f32x2 rd  = {0.f, 0.f};
#pragma unroll
        for (int j = 0; j < MPH; j++) {
            float4 q = wp4[t * 16 + (j >> 1)];
            f32x2 w2 = (j & 1) ? (f32x2){q.z, q.w} : (f32x2){q.x, q.y};
            rd = rd + w2 * Mv[j];                   // read uses PRE-update Mv
            f32x2 s = ne2 * Mv[j] + a2;             // a - e*Mv
            Mv[j] = Mv[j] + w2 * s;
        }
        float r = rd.x + rd.y;
        r += __shfl_xor(r, 32, 64);                 // combine the two m-halves
        if (mh == 0) Rb[t * DVV] = r;
        e0 = e1; e1 = en;
    }
}

__global__ __launch_bounds__(512, 2) void k_scan(const float* __restrict__ w_pad,
                                                 const float* __restrict__ EA,
                                                 const float* __restrict__ init_mv,
                                                 float* __restrict__ R) {
    __shared__ float Wl[SS * WROW];    // 51.2 KB: this block's w tile
    __shared__ float Sb[52 * 32];      // 6.5 KB boundary state (52 m-rows x 32 v)
    int b   = blockIdx.x >> 2;
    int vq  = blockIdx.x & 3;
    int tid = threadIdx.x;
    int lane  = tid & 63;
    int chunk = tid >> 6;              // wave id = chunk (0..7)
    int mh = lane >> 5;                // m-half (0: pairs 0-12, 1: pairs 13-25)
    int vl = lane & 31;
    int v  = vq * 32 + vl;
    int j0 = mh * MPH;                 // global pair offset 0 or 13 (Sb / init_mv)
    int t0 = chunk * CLEN;

    // stage w (coalesced float4), read once per block
    {
        const float4* wg = (const float4*)(w_pad + (long)b * SS * WROW);
        float4* wl4 = (float4*)Wl;
        for (int i = tid; i < SS * WROW / 4; i += 512) wl4[i] = wg[i];
    }
    __syncthreads();

    // aligned half base: floats t0*64 + mh*32 (128B-aligned) -> 7x ds_read_b128/step
    const float4* wp4 = (const float4*)(Wl + t0 * WROW + mh * 32);
    const float*  eab = EA + (((long)b * SS + t0) * DVV + v) * 2;
    float*        Rb  = R + ((long)b * SS + t0) * DVV + v;

    const f32x2 one = {1.f, 1.f};
    f32x2 A2[MPH], B2[MPH];
    f32x2 Mv[MPH];

    if (chunk == 0) {
        // real scan directly; final Mv IS the boundary for chunk 1
#pragma unroll
        for (int j = 0; j < MPH; j++) {
            int m0 = 2 * (j0 + j), m1 = m0 + 1;
            if (m0 > MM - 2) m0 = MM - 2;   // pad pair (m 50,51): w==0 there, value
            if (m1 > MM - 1) m1 = MM - 1;   // irrelevant but must stay in-bounds
            Mv[j].x = init_mv[m0 * DVV + v];
            Mv[j].y = init_mv[m1 * DVV + v];
        }
        scan_pass2(wp4, eab, Rb, mh, Mv);
#pragma unroll
        for (int j = 0; j < MPH; j++) {
            Sb[(2 * (j0 + j)) * 32 + vl] = Mv[j].x;
            Sb[(2 * (j0 + j) + 1) * 32 + vl] = Mv[j].y;
        }
    } else if (chunk < 7) {
#pragma unroll
        for (int j = 0; j < MPH; j++) { A2[j] = one; B2[j] = (f32x2){0.f, 0.f}; }
        scan_pass1(wp4, eab, A2, B2);
    }
    // chunk 7: no pass 1 needed (its A,B was never consumed)
    __syncthreads();

    for (int c = 1; c < 8; c++) {
        if (chunk == c) {
#pragma unroll
            for (int j = 0; j < MPH; j++) {
                Mv[j].x = Sb[(2 * (j0 + j)) * 32 + vl];
                Mv[j].y = Sb[(2 * (j0 + j) + 1) * 32 + vl];
            }
            if (c < 7) {
#pragma unroll
                for (int j = 0; j < MPH; j++) {
                    f32x2 nb = A2[j] * Mv[j] + B2[j];
                    Sb[(2 * (j0 + j)) * 32 + vl] = nb.x;
                    Sb[(2 * (j0 + j) + 1) * 32 + vl] = nb.y;
                }
            }
        }
        __syncthreads();
    }

    if (chunk > 0) scan_pass2(wp4, eab, Rb, mh, Mv);
}

// ---------------- Kernel 3: FC head via bf16 MFMA + BCE + fused loss ----------------
// 64 rows x 64 f per block, 4 waves. K=192 ([R||q_e]). read_w staged bf16 in LDS
// (25.6 KB -> 6 blocks/CU). A-frags global->reg. D: col=f=lane&15, row=quad*4+reg.
__global__ __launch_bounds__(256) void k_fc(const float* __restrict__ Rr,
                                            const int* __restrict__ q_data,
                                            const float* __restrict__ q_embed_w,
                                            const float* __restrict__ read_w,
                                            const float* __restrict__ read_b,
                                            const float* __restrict__ pred_w,
                                            const float* __restrict__ pred_b,
                                            const float* __restrict__ target,
                                            float* __restrict__ out,
                                            float* __restrict__ acc) {
    __shared__ short Wl[64 * FLDS];   // 25.6 KB
    __shared__ float2 red[4];
    int tid = threadIdx.x;
    int r0 = blockIdx.x * 64;
    int lane = tid & 63;
    int wv = tid >> 6;          // wave 0..3
    int n = lane & 15;
    int quad = lane >> 4;       // 0..3

    // stage read_w -> bf16 LDS (64 f-rows x 48 float4)
    for (int i = tid; i < 3072; i += 256) {
        int f = i / 48, p = i - f * 48;
        float4 src = *(const float4*)(read_w + f * 192 + p * 4);
        short4 d;
        d.x = f2bf(src.x); d.y = f2bf(src.y); d.z = f2bf(src.z); d.w = f2bf(src.w);
        *(short4*)(Wl + f * FLDS + p * 4) = d;
    }

    // A-frags: row = r0 + wv*16 + n; k = kb*32 + quad*8 + j; kb 0..3 from R, 4..5 from q_e
    int arow = r0 + wv * 16 + n;
    const float* rp = Rr + (long)arow * DVV + quad * 8;
    int qi = q_data[arow];
    const float* qp = q_embed_w + (long)qi * DKK + quad * 8;
    bf16x8 afrag[6];
#pragma unroll
    for (int kb = 0; kb < 4; kb++) afrag[kb] = cvt8(rp + kb * 32);
#pragma unroll
    for (int kb = 0; kb < 2; kb++) afrag[4 + kb] = cvt8(qp + kb * 32);

    // per-lane epilogue constants for f = ft*16+n
    float rb_[4], pw_[4];
#pragma unroll
    for (int ft = 0; ft < 4; ft++) {
        rb_[ft] = read_b[ft * 16 + n];
        pw_[ft] = pred_w[ft * 16 + n];
    }
    float pb = pred_b[0];
    __syncthreads();

    int rowbase = r0 + wv * 16 + quad * 4;
    float pv[4] = {0.f, 0.f, 0.f, 0.f};   // pred-dot partials per row-reg
#pragma unroll
    for (int ft = 0; ft < 4; ft++) {
        int f = ft * 16 + n;               // B-frag: lane's column = read_w row
        f32x4 ac = {0.f, 0.f, 0.f, 0.f};
#pragma unroll
        for (int kb = 0; kb < 6; kb++) {
            bf16x8 bfr = *(const bf16x8*)(Wl + f * FLDS + kb * 32 + quad * 8);
            ac = __builtin_amdgcn_mfma_f32_16x16x32_bf16(afrag[kb], bfr, ac, 0, 0, 0);
        }
        float rb = rb_[ft], pw = pw_[ft];
#pragma unroll
        for (int r = 0; r < 4; r++) {
            float h = 2.f / (1.f + __expf(-2.f * (ac[r] + rb))) - 1.f;   // tanh
            pv[r] = fmaf(pw, h, pv[r]);
        }
    }

    float bce_sum = 0.f, cnt = 0.f;
#pragma unroll
    for (int r = 0; r < 4; r++) {
        float p = pv[r];
        p += __shfl_xor(p, 1, 64);
        p += __shfl_xor(p, 2, 64);
        p += __shfl_xor(p, 4, 64);
        p += __shfl_xor(p, 8, 64);
        if (n == 0) {
            int row = rowbase + r;
            float tgt = target[row];
            float logit = p + pb;
            float prob = 0.f;
            if (tgt >= 0.f) {
                prob = 1.f / (1.f + __expf(-logit));
                float bce = fmaxf(logit, 0.f) - logit * tgt + log1pf(__expf(-fabsf(logit)));
                bce_sum += bce;
                cnt += 1.f;
            }
            out[1 + row] = prob;
        }
    }
    // reduce over quads (values live on lanes 0,16,32,48)
    bce_sum += __shfl_xor(bce_sum, 16, 64);
    bce_sum += __shfl_xor(bce_sum, 32, 64);
    cnt     += __shfl_xor(cnt, 16, 64);
    cnt     += __shfl_xor(cnt, 32, 64);
    if (lane == 0) { red[wv].x = bce_sum; red[wv].y = cnt; }
    __syncthreads();
    if (tid == 0) {
        float bsum = red[0].x + red[1].x + red[2].x + red[3].x;
        float csum = red[0].y + red[1].y + red[2].y + red[3].y;
        atomicAdd(&acc[0], bsum);
        atomicAdd(&acc[1], csum);
        __threadfence();
        unsigned prev = atomicAdd((unsigned*)acc + 2, 1u);
        if (prev == NFCB - 1) {          // last block computes the loss
            __threadfence();
            float B = atomicAdd(&acc[0], 0.f);
            float C = atomicAdd(&acc[1], 0.f);
            out[0] = B / fmaxf(C, 1.f);
        }
    }
}

extern "C" void kernel_launch(void* const* d_in, const int* in_sizes, int n_in,
                              void* d_out, int out_size, void* d_ws, size_t ws_size,
                              hipStream_t stream) {
    const int*   q_data     = (const int*)d_in[0];
    const int*   qa_data    = (const int*)d_in[1];
    const float* target     = (const float*)d_in[2];
    const float* q_embed_w  = (const float*)d_in[3];
    const float* qa_embed_w = (const float*)d_in[4];
    const float* mem_key    = (const float*)d_in[5];
    const float* init_mv    = (const float*)d_in[6];
    const float* erase_w    = (const float*)d_in[7];
    const float* erase_b    = (const float*)d_in[8];
    const float* add_w      = (const float*)d_in[9];
    const float* add_b      = (const float*)d_in[10];
    const float* read_w     = (const float*)d_in[11];
    const float* read_b     = (const float*)d_in[12];
    const float* pred_w     = (const float*)d_in[13];
    const float* pred_b     = (const float*)d_in[14];
    float* out = (float*)d_out;
    float* ws  = (float*)d_ws;

    float* w_all = ws + W_OFF;
    float* EA    = ws + EA_OFF;
    float* R     = ws + R_OFF;
    float* acc   = ws + ACC_OFF;

    k_pre<<<NSCB + NROW / 64, 256, 0, stream>>>(q_data, q_embed_w, mem_key,
                                                qa_data, qa_embed_w,
                                                erase_w, erase_b, add_w, add_b,
                                                w_all, EA, acc);
    k_scan<<<BB * 4, 512, 0, stream>>>(w_all, EA, init_mv, R);
    k_fc<<<NFCB, 256, 0, stream>>>(R, q_data, q_embed_w, read_w, read_b,
                                   pred_w, pred_b, target, out, acc);
}

// Round 14
// 171.262 us; speedup vs baseline: 1.0966x; 1.0062x over previous
//
#include <hip/hip_runtime.h>
#include <math.h>

#define BB 128
#define SS 200
#define MM 50
#define DKK 64
#define DVV 128
#define FF 64
#define NROW (BB*SS)   // 25600

#define WROW 64        // w padded layout: half0 m0-25 @ 0..25, half1 m26-49 @ 32..55, rest zero
#define NFCB (NROW/64) // 400 k_fc blocks
#define WLDS 136       // k_pre/ea LDS bf16 row stride (2-way bank alias = free)
#define FLDS 200       // k_fc LDS bf16 read_w row stride (192+8)
#define CLEN 25        // scan: steps per chunk (8 chunks x 25 = 200)
#define MPH 13         // scan: m-pairs per half-wave (26 pairs total; pair 25 = pad)
#define NSCB 100       // scores blocks inside k_pre (256 items each)

// workspace layout (floats)
#define W_OFF   0L
#define EA_OFF  (W_OFF + (long)NROW*WROW)        // interleaved (e,a) float2
#define R_OFF   (EA_OFF + (long)NROW*DVV*2)      // R now bf16 (ushort) — half the region used
#define ACC_OFF (R_OFF + (long)NROW*DVV)         // [0]=bce [1]=cnt [2]=counter bits

typedef __attribute__((ext_vector_type(8))) short bf16x8;   // 8 bf16 (4 VGPRs)
typedef __attribute__((ext_vector_type(4))) float f32x4;
typedef __attribute__((ext_vector_type(2))) float f32x2;    // -> v_pk_*_f32

__device__ __forceinline__ short f2bf(float f) {   // RNE fp32->bf16
    unsigned u = __builtin_bit_cast(unsigned, f);
    u += 0x7fff + ((u >> 16) & 1);
    return (short)(u >> 16);
}
__device__ __forceinline__ bf16x8 cvt8(const float* p) {
    float4 lo = *(const float4*)p;
    float4 hi = *(const float4*)(p + 4);
    bf16x8 f;
    f[0] = f2bf(lo.x); f[1] = f2bf(lo.y); f[2] = f2bf(lo.z); f[3] = f2bf(lo.w);
    f[4] = f2bf(hi.x); f[5] = f2bf(hi.y); f[6] = f2bf(hi.z); f[7] = f2bf(hi.w);
    return f;
}

// ---------------- Kernel 1: fused scores + ea (independent block types) ----------------
__global__ __launch_bounds__(256) void k_pre(const int* __restrict__ q_data,
                                             const float* __restrict__ q_embed_w,
                                             const float* __restrict__ mem_key,
                                             const int* __restrict__ qa_data,
                                             const float* __restrict__ qa_embed_w,
                                             const float* __restrict__ erase_w,
                                             const float* __restrict__ erase_b,
                                             const float* __restrict__ add_w,
                                             const float* __restrict__ add_b,
                                             float* __restrict__ w_out,
                                             float* __restrict__ EA,
                                             float* __restrict__ acc) {
    __shared__ union {
        short  wl[2 * 128 * WLDS];   // ea branch: bf16 weights, 69.6 KB
        float4 mk[MM * 16];          // scores branch: mem_key, 12.8 KB
    } sh;
    int tid = threadIdx.x;
    int bid = blockIdx.x;

    if (bid < NSCB) {
        // ---------- scores branch ----------
        if (bid == 0 && tid == 0) {
            acc[0] = 0.f; acc[1] = 0.f;
            ((unsigned*)acc)[2] = 0u;
        }
        const float4* mkg = (const float4*)mem_key;
        for (int i = tid; i < MM * 16; i += 256) sh.mk[i] = mkg[i];
        __syncthreads();

        int item = bid * 256 + tid;
        int qidx = q_data[item];
        const float4* qg = (const float4*)(q_embed_w + (long)qidx * DKK);
        float4 q[16];
#pragma unroll
        for (int i = 0; i < 16; i++) q[i] = qg[i];

        float s[MM];
        float mx = -1e30f;
#pragma unroll 2
        for (int m = 0; m < MM; m++) {
            float a = 0.f;
#pragma unroll
            for (int k4 = 0; k4 < 16; k4++) {
                float4 mkv = sh.mk[m * 16 + k4];
                float4 qv = q[k4];
                a = fmaf(qv.x, mkv.x, a);
                a = fmaf(qv.y, mkv.y, a);
                a = fmaf(qv.z, mkv.z, a);
                a = fmaf(qv.w, mkv.w, a);
            }
            s[m] = a;
            mx = fmaxf(mx, a);
        }
        float sum = 0.f;
#pragma unroll
        for (int m = 0; m < MM; m++) { s[m] = expf(s[m] - mx); sum += s[m]; }
        float inv = 1.f / sum;

        // aligned-half layout: m<26 at [m]; m>=26 at [m+6] (half1 base = float 32);
        // zeros at 26..31 and 56..63 so every half-slice is 128B-aligned for b128 reads
        float* wo = w_out + (long)item * WROW;
#pragma unroll
        for (int m = 0; m < 26; m++) wo[m] = s[m] * inv;
#pragma unroll
        for (int m = 26; m < MM; m++) wo[m + 6] = s[m] * inv;
#pragma unroll
        for (int m = 26; m < 32; m++) wo[m] = 0.f;
#pragma unroll
        for (int m = MM + 6; m < WROW; m++) wo[m] = 0.f;
        return;
    }

    // ---------- ea branch ----------
    int r0 = (bid - NSCB) * 64;
    int lane = tid & 63;
    int wv = tid >> 6;          // wave 0..3
    int n = lane & 15;
    int quad = lane >> 4;       // 0..3

    for (int i = tid; i < 8192; i += 256) {
        int mat = i >> 12;
        int r = (i >> 5) & 127;
        int p = i & 31;
        float4 src = *(const float4*)((mat ? add_w : erase_w) + r * 128 + p * 4);
        short4 d;
        d.x = f2bf(src.x); d.y = f2bf(src.y); d.z = f2bf(src.z); d.w = f2bf(src.w);
        *(short4*)(sh.wl + (mat * 128 + r) * WLDS + p * 4) = d;
    }

    int arow = r0 + wv * 16 + n;
    int qidx = qa_data[arow];
    const float* qp = qa_embed_w + (long)qidx * DVV + quad * 8;
    bf16x8 afrag[4];
#pragma unroll
    for (int kb = 0; kb < 4; kb++) afrag[kb] = cvt8(qp + kb * 32);

    float eb_[8], ab_[8];
#pragma unroll
    for (int vt = 0; vt < 8; vt++) {
        eb_[vt] = erase_b[vt * 16 + n];
        ab_[vt] = add_b[vt * 16 + n];
    }
    __syncthreads();

    int rowbase = r0 + wv * 16 + quad * 4;
#pragma unroll 2
    for (int vt = 0; vt < 8; vt++) {
        int vrow = vt * 16 + n;
        f32x4 ae = {0.f, 0.f, 0.f, 0.f};
        f32x4 aa = {0.f, 0.f, 0.f, 0.f};
#pragma unroll
        for (int kb = 0; kb < 4; kb++) {
            bf16x8 be = *(const bf16x8*)(sh.wl + vrow * WLDS + kb * 32 + quad * 8);
            bf16x8 ba = *(const bf16x8*)(sh.wl + (128 + vrow) * WLDS + kb * 32 + quad * 8);
            ae = __builtin_amdgcn_mfma_f32_16x16x32_bf16(afrag[kb], be, ae, 0, 0, 0);
            aa = __builtin_amdgcn_mfma_f32_16x16x32_bf16(afrag[kb], ba, aa, 0, 0, 0);
        }
        int v = vt * 16 + n;
        float eb = eb_[vt], ab = ab_[vt];
#pragma unroll
        for (int r = 0; r < 4; r++) {
            float ev = 1.f / (1.f + __expf(-(ae[r] + eb)));
            float av = 2.f / (1.f + __expf(-2.f * (aa[r] + ab))) - 1.f;
            float2 o; o.x = ev; o.y = av;
            *(float2*)(EA + (((long)(rowbase + r)) * DVV + v) * 2) = o;
        }
    }
}

// ---------------- Kernel 2: affine scan — R13 structure, R written as bf16 ----------------
// R13 (best, 172.3us total, k_scan ~37us): m-half split, b128-aligned w halves,
//   4 waves/SIMD, no spill.
// R14: k_fc converts R fp32->bf16 (RNE) anyway for its MFMA A-frags; do the conversion
//   in k_scan's epilogue instead. Bit-identical output; halves R write (12.8->6.4MB)
//   and k_fc's R read; deletes 32 f2bf per k_fc thread. No structural change.
__device__ __forceinline__ void scan_pass1(const float4* __restrict__ wp4,
                                           const float* __restrict__ eab,
                                           f32x2* A2, f32x2* B2) {
    const f32x2 one = {1.f, 1.f};
    float2 e0 = *(const float2*)eab;
    float2 e1 = *(const float2*)(eab + (long)1 * DVV * 2);
#pragma unroll 1
    for (int t = 0; t < CLEN; t++) {
        int tp = (t + 2 < CLEN) ? t + 2 : CLEN - 1;
        float2 en = *(const float2*)(eab + (long)tp * DVV * 2);
        f32x2 ne2 = {-e0.x, -e0.x};
        f32x2 a2  = {e0.y, e0.y};
#pragma unroll
        for (int j = 0; j < MPH; j++) {
            float4 q = wp4[t * 16 + (j >> 1)];
            f32x2 w2 = (j & 1) ? (f32x2){q.z, q.w} : (f32x2){q.x, q.y};
            f32x2 al = w2 * ne2 + one;              // 1 - w*e
            A2[j] = A2[j] * al;
            B2[j] = al * B2[j] + w2 * a2;
        }
        e0 = e1; e1 = en;
    }
}

__device__ __forceinline__ void scan_pass2(const float4* __restrict__ wp4,
                                           const float* __restrict__ eab,
                                           unsigned short* __restrict__ Rb, int mh,
                                           f32x2* Mv) {
    float2 e0 = *(const float2*)eab;
    float2 e1 = *(const float2*)(eab + (long)1 * DVV * 2);
#pragma unroll 1
    for (int t = 0; t < CLEN; t++) {
        int tp = (t + 2 < CLEN) ? t + 2 : CLEN - 1;
        float2 en = *(const float2*)(eab + (long)tp * DVV * 2);
        f32x2 ne2 = {-e0.x, -e0.x};
        f32x2 a2  = {e0.y, e0.y};
        f32x2 rd  = {0.f, 0.f};
#pragma unroll
        for (int j = 0; j < MPH; j++) {
            float4 q = wp4[t * 16 + (j >> 1)];
            f32x2 w2 = (j & 1) ? (f32x2){q.z, q.w} : (f32x2){q.x, q.y};
            rd = rd + w2 * Mv[j];                   // read uses PRE-update Mv
            f32x2 s = ne2 * Mv[j] + a2;             // a - e*Mv
            Mv[j] = Mv[j] + w2 * s;
        }
        float r = rd.x + rd.y;
        r += __shfl_xor(r, 32, 64);                 // combine the two m-halves
        if (mh == 0) Rb[t * DVV] = (unsigned short)f2bf(r);   // RNE, same as k_fc's cvt
        e0 = e1; e1 = en;
    }
}

__global__ __launch_bounds__(512, 2) void k_scan(const float* __restrict__ w_pad,
                                                 const float* __restrict__ EA,
                                                 const float* __restrict__ init_mv,
                                                 unsigned short* __restrict__ R) {
    __shared__ float Wl[SS * WROW];    // 51.2 KB: this block's w tile
    __shared__ float Sb[52 * 32];      // 6.5 KB boundary state (52 m-rows x 32 v)
    int b   = blockIdx.x >> 2;
    int vq  = blockIdx.x & 3;
    int tid = threadIdx.x;
    int lane  = tid & 63;
    int chunk = tid >> 6;              // wave id = chunk (0..7)
    int mh = lane >> 5;                // m-half (0: pairs 0-12, 1: pairs 13-25)
    int vl = lane & 31;
    int v  = vq * 32 + vl;
    int j0 = mh * MPH;                 // global pair offset 0 or 13 (Sb / init_mv)
    int t0 = chunk * CLEN;

    // stage w (coalesced float4), read once per block
    {
        const float4* wg = (const float4*)(w_pad + (long)b * SS * WROW);
        float4* wl4 = (float4*)Wl;
        for (int i = tid; i < SS * WROW / 4; i += 512) wl4[i] = wg[i];
    }
    __syncthreads();

    // aligned half base: floats t0*64 + mh*32 (128B-aligned) -> 7x ds_read_b128/step
    const float4* wp4 = (const float4*)(Wl + t0 * WROW + mh * 32);
    const float*  eab = EA + (((long)b * SS + t0) * DVV + v) * 2;
    unsigned short* Rb = R + ((long)b * SS + t0) * DVV + v;

    const f32x2 one = {1.f, 1.f};
    f32x2 A2[MPH], B2[MPH];
    f32x2 Mv[MPH];

    if (chunk == 0) {
        // real scan directly; final Mv IS the boundary for chunk 1
#pragma unroll
        for (int j = 0; j < MPH; j++) {
            int m0 = 2 * (j0 + j), m1 = m0 + 1;
            if (m0 > MM - 2) m0 = MM - 2;   // pad pair (m 50,51): w==0 there, value
            if (m1 > MM - 1) m1 = MM - 1;   // irrelevant but must stay in-bounds
            Mv[j].x = init_mv[m0 * DVV + v];
            Mv[j].y = init_mv[m1 * DVV + v];
        }
        scan_pass2(wp4, eab, Rb, mh, Mv);
#pragma unroll
        for (int j = 0; j < MPH; j++) {
            Sb[(2 * (j0 + j)) * 32 + vl] = Mv[j].x;
            Sb[(2 * (j0 + j) + 1) * 32 + vl] = Mv[j].y;
        }
    } else if (chunk < 7) {
#pragma unroll
        for (int j = 0; j < MPH; j++) { A2[j] = one; B2[j] = (f32x2){0.f, 0.f}; }
        scan_pass1(wp4, eab, A2, B2);
    }
    // chunk 7: no pass 1 needed (its A,B was never consumed)
    __syncthreads();

    for (int c = 1; c < 8; c++) {
        if (chunk == c) {
#pragma unroll
            for (int j = 0; j < MPH; j++) {
                Mv[j].x = Sb[(2 * (j0 + j)) * 32 + vl];
                Mv[j].y = Sb[(2 * (j0 + j) + 1) * 32 + vl];
            }
            if (c < 7) {
#pragma unroll
                for (int j = 0; j < MPH; j++) {
                    f32x2 nb = A2[j] * Mv[j] + B2[j];
                    Sb[(2 * (j0 + j)) * 32 + vl] = nb.x;
                    Sb[(2 * (j0 + j) + 1) * 32 + vl] = nb.y;
                }
            }
        }
        __syncthreads();
    }

    if (chunk > 0) scan_pass2(wp4, eab, Rb, mh, Mv);
}

// ---------------- Kernel 3: FC head via bf16 MFMA + BCE + fused loss ----------------
// 64 rows x 64 f per block, 4 waves. K=192 ([R||q_e]). read_w staged bf16 in LDS
// (25.6 KB -> 6 blocks/CU). R arrives as bf16 -> direct short8 loads, no cvt.
__global__ __launch_bounds__(256) void k_fc(const unsigned short* __restrict__ Rr,
                                            const int* __restrict__ q_data,
                                            const float* __restrict__ q_embed_w,
                                            const float* __restrict__ read_w,
                                            const float* __restrict__ read_b,
                                            const float* __restrict__ pred_w,
                                            const float* __restrict__ pred_b,
                                            const float* __restrict__ target,
                                            float* __restrict__ out,
                                            float* __restrict__ acc) {
    __shared__ short Wl[64 * FLDS];   // 25.6 KB
    __shared__ float2 red[4];
    int tid = threadIdx.x;
    int r0 = blockIdx.x * 64;
    int lane = tid & 63;
    int wv = tid >> 6;          // wave 0..3
    int n = lane & 15;
    int quad = lane >> 4;       // 0..3

    // stage read_w -> bf16 LDS (64 f-rows x 48 float4)
    for (int i = tid; i < 3072; i += 256) {
        int f = i / 48, p = i - f * 48;
        float4 src = *(const float4*)(read_w + f * 192 + p * 4);
        short4 d;
        d.x = f2bf(src.x); d.y = f2bf(src.y); d.z = f2bf(src.z); d.w = f2bf(src.w);
        *(short4*)(Wl + f * FLDS + p * 4) = d;
    }

    // A-frags: row = r0 + wv*16 + n; k = kb*32 + quad*8 + j; kb 0..3 from R (bf16 direct),
    // 4..5 from q_e (fp32 -> cvt)
    int arow = r0 + wv * 16 + n;
    const unsigned short* rp = Rr + (long)arow * DVV + quad * 8;
    int qi = q_data[arow];
    const float* qp = q_embed_w + (long)qi * DKK + quad * 8;
    bf16x8 afrag[6];
#pragma unroll
    for (int kb = 0; kb < 4; kb++) afrag[kb] = *(const bf16x8*)(rp + kb * 32);
#pragma unroll
    for (int kb = 0; kb < 2; kb++) afrag[4 + kb] = cvt8(qp + kb * 32);

    // per-lane epilogue constants for f = ft*16+n
    float rb_[4], pw_[4];
#pragma unroll
    for (int ft = 0; ft < 4; ft++) {
        rb_[ft] = read_b[ft * 16 + n];
        pw_[ft] = pred_w[ft * 16 + n];
    }
    float pb = pred_b[0];
    __syncthreads();

    int rowbase = r0 + wv * 16 + quad * 4;
    float pv[4] = {0.f, 0.f, 0.f, 0.f};   // pred-dot partials per row-reg
#pragma unroll
    for (int ft = 0; ft < 4; ft++) {
        int f = ft * 16 + n;               // B-frag: lane's column = read_w row
        f32x4 ac = {0.f, 0.f, 0.f, 0.f};
#pragma unroll
        for (int kb = 0; kb < 6; kb++) {
            bf16x8 bfr = *(const bf16x8*)(Wl + f * FLDS + kb * 32 + quad * 8);
            ac = __builtin_amdgcn_mfma_f32_16x16x32_bf16(afrag[kb], bfr, ac, 0, 0, 0);
        }
        float rb = rb_[ft], pw = pw_[ft];
#pragma unroll
        for (int r = 0; r < 4; r++) {
            float h = 2.f / (1.f + __expf(-2.f * (ac[r] + rb))) - 1.f;   // tanh
            pv[r] = fmaf(pw, h, pv[r]);
        }
    }

    float bce_sum = 0.f, cnt = 0.f;
#pragma unroll
    for (int r = 0; r < 4; r++) {
        float p = pv[r];
        p += __shfl_xor(p, 1, 64);
        p += __shfl_xor(p, 2, 64);
        p += __shfl_xor(p, 4, 64);
        p += __shfl_xor(p, 8, 64);
        if (n == 0) {
            int row = rowbase + r;
            float tgt = target[row];
            float logit = p + pb;
            float prob = 0.f;
            if (tgt >= 0.f) {
                prob = 1.f / (1.f + __expf(-logit));
                float bce = fmaxf(logit, 0.f) - logit * tgt + log1pf(__expf(-fabsf(logit)));
                bce_sum += bce;
                cnt += 1.f;
            }
            out[1 + row] = prob;
        }
    }
    // reduce over quads (values live on lanes 0,16,32,48)
    bce_sum += __shfl_xor(bce_sum, 16, 64);
    bce_sum += __shfl_xor(bce_sum, 32, 64);
    cnt     += __shfl_xor(cnt, 16, 64);
    cnt     += __shfl_xor(cnt, 32, 64);
    if (lane == 0) { red[wv].x = bce_sum; red[wv].y = cnt; }
    __syncthreads();
    if (tid == 0) {
        float bsum = red[0].x + red[1].x + red[2].x + red[3].x;
        float csum = red[0].y + red[1].y + red[2].y + red[3].y;
        atomicAdd(&acc[0], bsum);
        atomicAdd(&acc[1], csum);
        __threadfence();
        unsigned prev = atomicAdd((unsigned*)acc + 2, 1u);
        if (prev == NFCB - 1) {          // last block computes the loss
            __threadfence();
            float B = atomicAdd(&acc[0], 0.f);
            float C = atomicAdd(&acc[1], 0.f);
            out[0] = B / fmaxf(C, 1.f);
        }
    }
}

extern "C" void kernel_launch(void* const* d_in, const int* in_sizes, int n_in,
                              void* d_out, int out_size, void* d_ws, size_t ws_size,
                              hipStream_t stream) {
    const int*   q_data     = (const int*)d_in[0];
    const int*   qa_data    = (const int*)d_in[1];
    const float* target     = (const float*)d_in[2];
    const float* q_embed_w  = (const float*)d_in[3];
    const float* qa_embed_w = (const float*)d_in[4];
    const float* mem_key    = (const float*)d_in[5];
    const float* init_mv    = (const float*)d_in[6];
    const float* erase_w    = (const float*)d_in[7];
    const float* erase_b    = (const float*)d_in[8];
    const float* add_w      = (const float*)d_in[9];
    const float* add_b      = (const float*)d_in[10];
    const float* read_w     = (const float*)d_in[11];
    const float* read_b     = (const float*)d_in[12];
    const float* pred_w     = (const float*)d_in[13];
    const float* pred_b     = (const float*)d_in[14];
    float* out = (float*)d_out;
    float* ws  = (float*)d_ws;

    float* w_all = ws + W_OFF;
    float* EA    = ws + EA_OFF;
    unsigned short* R = (unsigned short*)(ws + R_OFF);
    float* acc   = ws + ACC_OFF;

    k_pre<<<NSCB + NROW / 64, 256, 0, stream>>>(q_data, q_embed_w, mem_key,
                                                qa_data, qa_embed_w,
                                                erase_w, erase_b, add_w, add_b,
                                                w_all, EA, acc);
    k_scan<<<BB * 4, 512, 0, stream>>>(w_all, EA, init_mv, R);
    k_fc<<<NFCB, 256, 0, stream>>>(R, q_data, q_embed_w, read_w, read_b,
                                   pred_w, pred_b, target, out, acc);
}